// Round 2
// 63.631 us; speedup vs baseline: 1.0497x; 1.0497x over previous
//
#include <hip/hip_runtime.h>
#include <utility>

#define NQB   12
#define NST   4096
#define NLAY  6
#define NCLS  64
#define NGQ   72      // 6 layers x 12 RX gates (sample-independent)
#define TPB   512
#define RS    10      // d row stride in float2 (80 B: 16B-aligned, bank-clean)
#define ZST   516     // zmat row stride in dwords (16B-aligned rows)

// ---------------- compile-time mask computation (GF(2) circuit algebra) ----
// The CNOT ring / basis change depends only on circuit structure, never on
// data, so the full mask set folds to literals in the ISA.

struct Masks { int m[NGQ]; int em[NQB]; };

constexpr int pc_c(unsigned v) { int c = 0; while (v) { c += (int)(v & 1u); v >>= 1; } return c; }

constexpr int f_of_c(int j) {
    // one layer's CNOT ring (natural basis: wire w <-> bit 11-w)
    for (int w = 11; w >= 0; --w) {
        int pc = 11 - w;
        int pt = 11 - ((w + 1) % 12);
        j ^= ((j >> pc) & 1) << pt;
    }
    return j;
}

constexpr Masks build_masks() {
    Masks M{};
    // natural-basis layer masks: layer l, wire w -> f^l(2^(11-w))
    int lm[NGQ] = {};
    for (int l = 0; l < NLAY; ++l)
        for (int w = 0; w < NQB; ++w) {
            int v = 1 << (11 - w);
            for (int t = 0; t < l; ++t) v = f_of_c(v);
            lm[l * NQB + w] = v;
        }
    // natural-basis measurement parities: rows of (f^6)^-1 over GF(2)
    int col[NQB] = {};
    for (int k = 0; k < NQB; ++k) {
        int v = 1 << k;
        for (int t = 0; t < NLAY; ++t) v = f_of_c(v);
        col[k] = v;
    }
    unsigned rowG[NQB] = {}, rowH[NQB] = {};
    for (int r = 0; r < NQB; ++r) {
        unsigned rr = 0;
        for (int k = 0; k < NQB; ++k) rr |= ((unsigned)((col[k] >> r) & 1)) << k;
        rowG[r] = rr;
        rowH[r] = 1u << r;
    }
    for (int k = 0; k < NQB; ++k) {                  // Gauss-Jordan over GF(2)
        int piv = -1;
        for (int r = k; r < NQB; ++r)
            if ((rowG[r] >> k) & 1) { piv = r; break; }
        unsigned tg = rowG[piv], th = rowH[piv];
        rowG[piv] = rowG[k]; rowH[piv] = rowH[k];
        rowG[k] = tg; rowH[k] = th;
        for (int r = 0; r < NQB; ++r)
            if (r != k && ((rowG[r] >> k) & 1)) { rowG[r] ^= rowG[k]; rowH[r] ^= rowH[k]; }
    }
    int meas_nat[NQB] = {};
    for (int w = 0; w < NQB; ++w) meas_nat[w] = (int)rowH[11 - w];

    // Basis change S with S(t_w) = e_w. Masks transform by S^-T:
    // bit b of m' = parity(popc(Tm[b] & m)).
    int Tm[NQB] = {};
    for (int w = 0; w < NQB; ++w) Tm[w] = meas_nat[w];
    for (int g = 0; g < NGQ; ++g) {
        int mm = lm[g], o = 0;
        for (int bb = 0; bb < NQB; ++bb)
            if (pc_c((unsigned)(Tm[bb] & mm)) & 1) o |= 1 << bb;
        M.m[g] = o;
    }
    for (int w = 0; w < NQB; ++w) {
        int mm = 1 << (11 - w), o = 0;               // embedding RX on wire w
        for (int bb = 0; bb < NQB; ++bb)
            if (pc_c((unsigned)(Tm[bb] & mm)) & 1) o |= 1 << bb;
        M.em[w] = o;
    }
    return M;
}

constexpr Masks MK = build_masks();

// guaranteed-static unroller: indices are constant expressions, so the
// C[8] class accumulators stay in registers (no runtime indexing).
template <typename F, int... Is>
__device__ __forceinline__ void static_for_impl(F f, std::integer_sequence<int, Is...>) {
    (f(std::integral_constant<int, Is>{}), ...);
}
template <int N, typename F>
__device__ __forceinline__ void static_for(F f) {
    static_for_impl(f, std::make_integer_sequence<int, N>{});
}

// ---- fused kernel: phases (layer + embedding via 8-class FWHT), ----------
// ---- single-bit-mask Walsh autocorrelation, classifier head     ----------
__global__ __launch_bounds__(TPB) void qnn_kernel(
    const float* __restrict__ x, const float* __restrict__ qw,
    const float* __restrict__ W, const float* __restrict__ bias,
    float* __restrict__ out)
{
    __shared__ float2 dd[TPB * RS];        // d[tid][r], padded rows
    __shared__ float  zmat[NQB * ZST];     // per-thread partials, [w][tid]
    __shared__ float  part2[NQB * 32];
    __shared__ float  zfin[NQB];

    const int tid = threadIdx.x;
    const int b   = blockIdx.x;

    // phase classes: phi(tid | r<<9) = sum_h (-1)^{popc(r&h)} C[h],
    // C[h] = sum over gates with hi-class h of (-1)^{popc(tid&lo)} * 0.5*coef
    float C[8];
    #pragma unroll
    for (int h = 0; h < 8; ++h) C[h] = 0.f;

    static_for<NGQ>([&](auto gc) {                  // layer gates (qw, uniform)
        constexpr int g  = decltype(gc)::value;
        constexpr int mg = MK.m[g];
        constexpr int lo = mg & 511;
        constexpr int hi = mg >> 9;
        float v = 0.5f * qw[g];                     // uniform -> scalar load
        C[hi] += (__popc(tid & lo) & 1) ? -v : v;
    });
    static_for<NQB>([&](auto wc) {                  // embedding gates (x[b,:])
        constexpr int w  = decltype(wc)::value;
        constexpr int mg = MK.em[w];
        constexpr int lo = mg & 511;
        constexpr int hi = mg >> 9;
        float v = 0.5f * x[b * NQB + w];            // uniform -> scalar load
        C[hi] += (__popc(tid & lo) & 1) ? -v : v;
    });

    // 3-bit fast Walsh-Hadamard: C[r] becomes the phase for slab r
    #define BFLY(i, j) { float a_ = C[i], b_ = C[j]; C[i] = a_ + b_; C[j] = a_ - b_; }
    BFLY(0,1) BFLY(2,3) BFLY(4,5) BFLY(6,7)
    BFLY(0,2) BFLY(1,3) BFLY(4,6) BFLY(5,7)
    BFLY(0,4) BFLY(1,5) BFLY(2,6) BFLY(3,7)
    #undef BFLY

    float2 myd[8];
    #pragma unroll
    for (int r = 0; r < 8; ++r) {
        float phi = C[r];
        // v_sin/v_cos take revolutions; phi ~1e2 rad -> ~1e-5 phase error,
        // far under the 6e-4 absmax threshold
        float rv = phi * 0.15915494309189535f;
        rv -= floorf(rv);
        myd[r] = make_float2(__builtin_amdgcn_cosf(rv),
                             __builtin_amdgcn_sinf(rv));
    }
    // write own row as 4 x b128 (80 B row stride: conflict-free)
    {
        float4* wr = (float4*)&dd[tid * RS];
        #pragma unroll
        for (int h = 0; h < 4; ++h)
            wr[h] = make_float4(myd[2 * h].x, myd[2 * h].y,
                                myd[2 * h + 1].x, myd[2 * h + 1].y);
    }
    __syncthreads();

    // z_w for meas mask e_p. p<6: lane bit (exec-masked half, pairs once);
    // p=6..8: wave bit (wave-uniform skip); p=9..11: register slab bit.
    float acc[NQB];
    #pragma unroll
    for (int p = 0; p < 9; ++p) {
        float aw = 0.f;
        if (!((tid >> p) & 1)) {
            const float4* row = (const float4*)&dd[(tid ^ (1 << p)) * RS];
            #pragma unroll
            for (int h = 0; h < 4; ++h) {
                float4 q = row[h];                 // (c,s) for r=2h, 2h+1
                aw = fmaf(myd[2 * h].x, q.x, fmaf(myd[2 * h].y, q.y, aw));
                aw = fmaf(myd[2 * h + 1].x, q.z,
                          fmaf(myd[2 * h + 1].y, q.w, aw));
            }
        }
        acc[p] = aw;
    }
    {
        auto dot2 = [&](int i, int j) {
            return fmaf(myd[i].x, myd[j].x, myd[i].y * myd[j].y);
        };
        acc[9]  = dot2(0,1) + dot2(2,3) + dot2(4,5) + dot2(6,7);  // r^1 pairs
        acc[10] = dot2(0,2) + dot2(1,3) + dot2(4,6) + dot2(5,7);  // r^2 pairs
        acc[11] = dot2(0,4) + dot2(1,5) + dot2(2,6) + dot2(3,7);  // r^4 pairs
    }

    // two-stage LDS reduction (replaces 72 shfl ops on the LDS pipe)
    #pragma unroll
    for (int w = 0; w < NQB; ++w) zmat[w * ZST + tid] = acc[w];
    __syncthreads();
    if (tid < NQB * 32) {
        const int w = tid >> 5, seg = tid & 31;
        const float4* rowz = (const float4*)&zmat[w * ZST];
        float s = 0.f;
        #pragma unroll
        for (int i = 0; i < 4; ++i) {
            float4 q = rowz[seg * 4 + i];
            s += (q.x + q.y) + (q.z + q.w);
        }
        part2[w * 32 + seg] = s;
    }
    __syncthreads();
    if (tid < NQB) {
        float s = 0.f;
        #pragma unroll
        for (int i = 0; i < 32; ++i) s += part2[tid * 32 + i];
        zfin[tid] = s * (2.0f / NST);   // every pair counted once -> x2
    }
    __syncthreads();

    // classifier head
    if (tid < NCLS) {
        float a = bias[tid];
        #pragma unroll
        for (int w = 0; w < NQB; ++w) a += zfin[w] * W[tid * NQB + w];
        out[b * NCLS + tid] = a;
    }
}

extern "C" void kernel_launch(void* const* d_in, const int* in_sizes, int n_in,
                              void* d_out, int out_size, void* d_ws, size_t ws_size,
                              hipStream_t stream) {
    const float* x    = (const float*)d_in[0];
    const float* qw   = (const float*)d_in[1];
    const float* W    = (const float*)d_in[2];
    const float* bias = (const float*)d_in[3];
    float* out        = (float*)d_out;
    (void)d_ws; (void)ws_size;

    const int batch = in_sizes[0] / NQB;   // in_sizes is in ELEMENTS -> 512
    qnn_kernel<<<batch, TPB, 0, stream>>>(x, qw, W, bias, out);
}

// Round 3
// 63.096 us; speedup vs baseline: 1.0586x; 1.0085x over previous
//
#include <hip/hip_runtime.h>
#include <utility>

#define NQB   12
#define NST   4096
#define NLAY  6
#define NCLS  64
#define NGQ   72      // 6 layers x 12 RX gates (sample-independent)
#define TPB   512
#define RS    10      // d row stride in float2 (80 B: 16B-aligned, bank-clean)

// ---------------- compile-time mask computation (GF(2) circuit algebra) ----
// The CNOT ring / basis change depends only on circuit structure, never on
// data, so the full mask set folds to literals in the ISA.

struct Masks { int m[NGQ]; int em[NQB]; };

constexpr int pc_c(unsigned v) { int c = 0; while (v) { c += (int)(v & 1u); v >>= 1; } return c; }

constexpr int f_of_c(int j) {
    // one layer's CNOT ring (natural basis: wire w <-> bit 11-w)
    for (int w = 11; w >= 0; --w) {
        int pc = 11 - w;
        int pt = 11 - ((w + 1) % 12);
        j ^= ((j >> pc) & 1) << pt;
    }
    return j;
}

constexpr Masks build_masks() {
    Masks M{};
    // natural-basis layer masks: layer l, wire w -> f^l(2^(11-w))
    int lm[NGQ] = {};
    for (int l = 0; l < NLAY; ++l)
        for (int w = 0; w < NQB; ++w) {
            int v = 1 << (11 - w);
            for (int t = 0; t < l; ++t) v = f_of_c(v);
            lm[l * NQB + w] = v;
        }
    // natural-basis measurement parities: rows of (f^6)^-1 over GF(2)
    int col[NQB] = {};
    for (int k = 0; k < NQB; ++k) {
        int v = 1 << k;
        for (int t = 0; t < NLAY; ++t) v = f_of_c(v);
        col[k] = v;
    }
    unsigned rowG[NQB] = {}, rowH[NQB] = {};
    for (int r = 0; r < NQB; ++r) {
        unsigned rr = 0;
        for (int k = 0; k < NQB; ++k) rr |= ((unsigned)((col[k] >> r) & 1)) << k;
        rowG[r] = rr;
        rowH[r] = 1u << r;
    }
    for (int k = 0; k < NQB; ++k) {                  // Gauss-Jordan over GF(2)
        int piv = -1;
        for (int r = k; r < NQB; ++r)
            if ((rowG[r] >> k) & 1) { piv = r; break; }
        unsigned tg = rowG[piv], th = rowH[piv];
        rowG[piv] = rowG[k]; rowH[piv] = rowH[k];
        rowG[k] = tg; rowH[k] = th;
        for (int r = 0; r < NQB; ++r)
            if (r != k && ((rowG[r] >> k) & 1)) { rowG[r] ^= rowG[k]; rowH[r] ^= rowH[k]; }
    }
    int meas_nat[NQB] = {};
    for (int w = 0; w < NQB; ++w) meas_nat[w] = (int)rowH[11 - w];

    // Basis change S with S(t_w) = e_w. Masks transform by S^-T:
    // bit b of m' = parity(popc(Tm[b] & m)).
    int Tm[NQB] = {};
    for (int w = 0; w < NQB; ++w) Tm[w] = meas_nat[w];
    for (int g = 0; g < NGQ; ++g) {
        int mm = lm[g], o = 0;
        for (int bb = 0; bb < NQB; ++bb)
            if (pc_c((unsigned)(Tm[bb] & mm)) & 1) o |= 1 << bb;
        M.m[g] = o;
    }
    for (int w = 0; w < NQB; ++w) {
        int mm = 1 << (11 - w), o = 0;               // embedding RX on wire w
        for (int bb = 0; bb < NQB; ++bb)
            if (pc_c((unsigned)(Tm[bb] & mm)) & 1) o |= 1 << bb;
        M.em[w] = o;
    }
    return M;
}

constexpr Masks MK = build_masks();

// compile-time dedup of layer-gate masks: gates with identical transformed
// masks merge into one vector sign-op over a scalar-summed coefficient.
struct MergedQ { int nd; int mask[NGQ]; int start[NGQ + 1]; int gidx[NGQ]; };

constexpr MergedQ merge_q() {
    MergedQ R{};
    bool used[NGQ] = {};
    int pos = 0;
    for (int g = 0; g < NGQ; ++g) {
        if (used[g]) continue;
        R.mask[R.nd] = MK.m[g];
        R.start[R.nd] = pos;
        for (int h = g; h < NGQ; ++h)
            if (!used[h] && MK.m[h] == MK.m[g]) { used[h] = true; R.gidx[pos++] = h; }
        ++R.nd;
    }
    R.start[R.nd] = pos;
    return R;
}

constexpr MergedQ MQ = merge_q();

// guaranteed-static unroller: indices are constant expressions, so the
// C[8] class accumulators stay in registers (no runtime indexing).
template <typename F, int... Is>
__device__ __forceinline__ void static_for_impl(F f, std::integer_sequence<int, Is...>) {
    (f(std::integral_constant<int, Is>{}), ...);
}
template <int N, typename F>
__device__ __forceinline__ void static_for(F f) {
    static_for_impl(f, std::make_integer_sequence<int, N>{});
}

// DPP wave-64 sum: canonical GCN 6-step (row_shr 1,2,4,8 + row_bcast 15,31).
// Pure VALU crossbar - no LDS pipe traffic. Full sum lands in lane 63.
template <int CTRL, int RM, int BM>
__device__ __forceinline__ float dpp_add(float x) {
    int t = __builtin_amdgcn_update_dpp(0, __float_as_int(x), CTRL, RM, BM, true);
    return x + __int_as_float(t);
}
__device__ __forceinline__ float wave_sum64(float x) {
    x = dpp_add<0x111, 0xF, 0xF>(x);   // row_shr:1
    x = dpp_add<0x112, 0xF, 0xF>(x);   // row_shr:2
    x = dpp_add<0x114, 0xF, 0xF>(x);   // row_shr:4
    x = dpp_add<0x118, 0xF, 0xF>(x);   // row_shr:8  -> lane 16r+15 = row sum
    x = dpp_add<0x142, 0xA, 0xF>(x);   // row_bcast:15 -> L31=R0+R1, L63=R2+R3
    x = dpp_add<0x143, 0xC, 0xF>(x);   // row_bcast:31 -> L63 = total
    return x;
}

// ---- fused kernel: phases (layer + embedding via 8-class FWHT), ----------
// ---- single-bit-mask Walsh autocorrelation, DPP reduce, head    ----------
__global__ __launch_bounds__(TPB) void qnn_kernel(
    const float* __restrict__ x, const float* __restrict__ qw,
    const float* __restrict__ W, const float* __restrict__ bias,
    float* __restrict__ out)
{
    __shared__ float2 dd[TPB * RS];              // d[tid][r], padded rows
    __shared__ __align__(16) float wsum[8 * NQB]; // per-wave z partials

    const int tid = threadIdx.x;
    const int b   = blockIdx.x;

    // phase classes: phi(tid | r<<9) = sum_h (-1)^{popc(r&h)} C[h].
    // 0.5x gate-angle factor is folded into the revolutions constant below.
    float C[8];
    #pragma unroll
    for (int h = 0; h < 8; ++h) C[h] = 0.f;

    static_for<MQ.nd>([&](auto ic) {            // layer gates (qw, uniform)
        constexpr int i  = decltype(ic)::value;
        constexpr int mg = MQ.mask[i];
        constexpr int lo = mg & 511;
        constexpr int hi = mg >> 9;
        constexpr int st = MQ.start[i];
        constexpr int cnt = MQ.start[i + 1] - st;
        float v = qw[MQ.gidx[st]];              // uniform -> scalar load
        static_for<cnt - 1>([&](auto jc) {
            constexpr int j = decltype(jc)::value;
            v += qw[MQ.gidx[st + 1 + j]];
        });
        C[hi] += (__popc(tid & lo) & 1) ? -v : v;
    });
    static_for<NQB>([&](auto wc) {              // embedding gates (x[b,:])
        constexpr int w  = decltype(wc)::value;
        constexpr int mg = MK.em[w];
        constexpr int lo = mg & 511;
        constexpr int hi = mg >> 9;
        float v = x[b * NQB + w];               // uniform -> scalar load
        C[hi] += (__popc(tid & lo) & 1) ? -v : v;
    });

    // 3-bit fast Walsh-Hadamard: C[r] becomes the (2x) phase for slab r
    #define BFLY(i, j) { float a_ = C[i], b_ = C[j]; C[i] = a_ + b_; C[j] = a_ - b_; }
    BFLY(0,1) BFLY(2,3) BFLY(4,5) BFLY(6,7)
    BFLY(0,2) BFLY(1,3) BFLY(4,6) BFLY(5,7)
    BFLY(0,4) BFLY(1,5) BFLY(2,6) BFLY(3,7)
    #undef BFLY

    float2 myd[8];
    #pragma unroll
    for (int r = 0; r < 8; ++r) {
        // v_sin/v_cos take revolutions; 0.5 (gate angle) folded in:
        // rv = phi * 0.5 / (2*pi). ~1e-5 phase error, far under threshold.
        float rv = C[r] * 0.07957747154594767f;
        rv -= floorf(rv);
        myd[r] = make_float2(__builtin_amdgcn_cosf(rv),
                             __builtin_amdgcn_sinf(rv));
    }
    // write own row as 4 x b128 (80 B row stride: conflict-free)
    {
        float4* wr = (float4*)&dd[tid * RS];
        #pragma unroll
        for (int h = 0; h < 4; ++h)
            wr[h] = make_float4(myd[2 * h].x, myd[2 * h].y,
                                myd[2 * h + 1].x, myd[2 * h + 1].y);
    }
    __syncthreads();

    // z_w for meas mask e_p. p<6: lane bit (exec-masked half, pairs once);
    // p=6..8: wave bit (wave-uniform skip); p=9..11: register slab bit.
    float acc[NQB];
    #pragma unroll
    for (int p = 0; p < 9; ++p) {
        float aw = 0.f;
        if (!((tid >> p) & 1)) {
            const float4* row = (const float4*)&dd[(tid ^ (1 << p)) * RS];
            #pragma unroll
            for (int h = 0; h < 4; ++h) {
                float4 q = row[h];                 // (c,s) for r=2h, 2h+1
                aw = fmaf(myd[2 * h].x, q.x, fmaf(myd[2 * h].y, q.y, aw));
                aw = fmaf(myd[2 * h + 1].x, q.z,
                          fmaf(myd[2 * h + 1].y, q.w, aw));
            }
        }
        acc[p] = aw;
    }
    {
        auto dot2 = [&](int i, int j) {
            return fmaf(myd[i].x, myd[j].x, myd[i].y * myd[j].y);
        };
        acc[9]  = dot2(0,1) + dot2(2,3) + dot2(4,5) + dot2(6,7);  // r^1 pairs
        acc[10] = dot2(0,2) + dot2(1,3) + dot2(4,6) + dot2(5,7);  // r^2 pairs
        acc[11] = dot2(0,4) + dot2(1,5) + dot2(2,6) + dot2(3,7);  // r^4 pairs
    }

    // DPP wave reduction (VALU crossbar, no LDS pipe, no extra barriers)
    #pragma unroll
    for (int w = 0; w < NQB; ++w) {
        float v = wave_sum64(acc[w]);
        if ((tid & 63) == 63) wsum[(tid >> 6) * NQB + w] = v;
    }
    __syncthreads();

    // classifier head: inline cross-wave reduce (24 broadcast b128 reads)
    if (tid < NCLS) {
        const float4* ws4 = (const float4*)wsum;
        float4 z0 = ws4[0], z1 = ws4[1], z2 = ws4[2];
        #pragma unroll
        for (int k = 1; k < 8; ++k) {
            float4 q0 = ws4[k * 3 + 0], q1 = ws4[k * 3 + 1], q2 = ws4[k * 3 + 2];
            z0.x += q0.x; z0.y += q0.y; z0.z += q0.z; z0.w += q0.w;
            z1.x += q1.x; z1.y += q1.y; z1.z += q1.z; z1.w += q1.w;
            z2.x += q2.x; z2.y += q2.y; z2.z += q2.z; z2.w += q2.w;
        }
        const float4* wr = (const float4*)&W[tid * NQB];   // 48 B rows, aligned
        float4 w0 = wr[0], w1 = wr[1], w2 = wr[2];
        float s = z0.x * w0.x + z0.y * w0.y + z0.z * w0.z + z0.w * w0.w
                + z1.x * w1.x + z1.y * w1.y + z1.z * w1.z + z1.w * w1.w
                + z2.x * w2.x + z2.y * w2.y + z2.z * w2.z + z2.w * w2.w;
        // every pair counted once -> x2; /NST normalization
        out[b * NCLS + tid] = fmaf(s, 2.0f / NST, bias[tid]);
    }
}

extern "C" void kernel_launch(void* const* d_in, const int* in_sizes, int n_in,
                              void* d_out, int out_size, void* d_ws, size_t ws_size,
                              hipStream_t stream) {
    const float* x    = (const float*)d_in[0];
    const float* qw   = (const float*)d_in[1];
    const float* W    = (const float*)d_in[2];
    const float* bias = (const float*)d_in[3];
    float* out        = (float*)d_out;
    (void)d_ws; (void)ws_size;

    const int batch = in_sizes[0] / NQB;   // in_sizes is in ELEMENTS -> 512
    qnn_kernel<<<batch, TPB, 0, stream>>>(x, qw, W, bias, out);
}